// Round 1
// baseline (669.166 us; speedup 1.0000x reference)
//
#include <hip/hip_runtime.h>
#include <math.h>

namespace {

constexpr int E_  = 768;
constexpr int H_  = 12;
constexpr int DH_ = 64;
constexpr int T_  = 2048;
constexpr int B_  = 2;

// ---------------------------------------------------------------------------
// QKV projection: Y[m, h*64+d] = sum_e x[m,e] * W[h,e,d]  for W in {Wq,Wk,Wv}
// grid.x = 36 (mat*12 + h), grid.y = 64 (m-tiles of 64). 256 threads.
// Output layout: ws[(b*H + h)][t][d]  (flash-attn friendly)
// ---------------------------------------------------------------------------
__global__ __launch_bounds__(256) void qkv_gemm_k(
    const float* __restrict__ x, const float* __restrict__ Wq,
    const float* __restrict__ Wk, const float* __restrict__ Wv,
    float* __restrict__ q_ws, float* __restrict__ k_ws, float* __restrict__ v_ws)
{
  __shared__ __align__(16) float As[16][68];  // [k][m], padded stride
  __shared__ __align__(16) float Bs[16][64];  // [k][d]

  const int bx  = blockIdx.x;          // 0..35
  const int m0  = blockIdx.y * 64;
  const int mat = bx / H_;
  const int h   = bx - mat * H_;
  const float* W    = (mat == 0) ? Wq : (mat == 1) ? Wk : Wv;
  const float* Wh   = W + (size_t)h * E_ * DH_;           // [768][64]
  float*       outw = (mat == 0) ? q_ws : (mat == 1) ? k_ws : v_ws;

  const int tid = threadIdx.x;
  const int tx  = tid & 15, ty = tid >> 4;   // 16x16 compute layout
  const int lr  = tid >> 2, lq = tid & 3;    // 64x4  A-loader layout

  float acc[4][4] = {};

  for (int k0 = 0; k0 < E_; k0 += 16) {
    // A tile 64x16, store transposed [k][m]
    float4 av = *(const float4*)(x + (size_t)(m0 + lr) * E_ + k0 + lq * 4);
    As[lq * 4 + 0][lr] = av.x;
    As[lq * 4 + 1][lr] = av.y;
    As[lq * 4 + 2][lr] = av.z;
    As[lq * 4 + 3][lr] = av.w;
    // B tile 16x64, natural [k][d]
    *(float4*)&Bs[ty][tx * 4] =
        *(const float4*)(Wh + (size_t)(k0 + ty) * DH_ + tx * 4);
    __syncthreads();
#pragma unroll
    for (int kk = 0; kk < 16; ++kk) {
      float4 a = *(const float4*)&As[kk][ty * 4];
      float4 b = *(const float4*)&Bs[kk][tx * 4];
      acc[0][0] += a.x * b.x; acc[0][1] += a.x * b.y; acc[0][2] += a.x * b.z; acc[0][3] += a.x * b.w;
      acc[1][0] += a.y * b.x; acc[1][1] += a.y * b.y; acc[1][2] += a.y * b.z; acc[1][3] += a.y * b.w;
      acc[2][0] += a.z * b.x; acc[2][1] += a.z * b.y; acc[2][2] += a.z * b.z; acc[2][3] += a.z * b.w;
      acc[3][0] += a.w * b.x; acc[3][1] += a.w * b.y; acc[3][2] += a.w * b.z; acc[3][3] += a.w * b.w;
    }
    __syncthreads();
  }

  const int b = m0 / T_;   // 64-row tile never straddles batch boundary
#pragma unroll
  for (int i = 0; i < 4; ++i) {
    const int t = m0 + ty * 4 + i - b * T_;
    float4 o = make_float4(acc[i][0], acc[i][1], acc[i][2], acc[i][3]);
    *(float4*)(outw + ((size_t)(b * H_ + h) * T_ + t) * DH_ + tx * 4) = o;
  }
}

// ---------------------------------------------------------------------------
// Causal flash attention, f32. grid.x = 32 q-tiles, grid.y = 24 (b*H + h).
// 256 threads; each computes a 4x4 patch of the 64x64 S tile / O tile.
// Online softmax state per q-row replicated across the row's 16 lanes.
// Output written in concat-heads layout o_ws[b][t][h*64+d].
// ---------------------------------------------------------------------------
__global__ __launch_bounds__(256) void attn_k(
    const float* __restrict__ q_ws, const float* __restrict__ k_ws,
    const float* __restrict__ v_ws, float* __restrict__ o_ws)
{
  __shared__ __align__(16) float Qt[64][68];  // [d][r]
  __shared__ __align__(16) float Kt[64][68];  // [d][s]
  __shared__ __align__(16) float Vs[64][68];  // [s][d]
  __shared__ __align__(16) float Pt[64][68];  // [s][r]

  const int qt = blockIdx.x;       // 0..31
  const int bh = blockIdx.y;       // 0..23
  const int q0 = qt * 64;
  const float* Qb = q_ws + (size_t)bh * T_ * DH_;
  const float* Kb = k_ws + (size_t)bh * T_ * DH_;
  const float* Vb = v_ws + (size_t)bh * T_ * DH_;

  const int tid = threadIdx.x;
  const int tx  = tid & 15, ty = tid >> 4;
  const int lr  = tid >> 2, lq = tid & 3;    // loader: row lr, 16-d chunk lq

  // stage Q transposed [d][r]
#pragma unroll
  for (int dd = 0; dd < 16; dd += 4) {
    float4 qv = *(const float4*)(Qb + (size_t)(q0 + lr) * DH_ + lq * 16 + dd);
    Qt[lq * 16 + dd + 0][lr] = qv.x;
    Qt[lq * 16 + dd + 1][lr] = qv.y;
    Qt[lq * 16 + dd + 2][lr] = qv.z;
    Qt[lq * 16 + dd + 3][lr] = qv.w;
  }

  float m_i[4], l_i[4], Oacc[4][4];
#pragma unroll
  for (int i = 0; i < 4; ++i) {
    m_i[i] = -INFINITY;
    l_i[i] = 0.f;
#pragma unroll
    for (int j = 0; j < 4; ++j) Oacc[i][j] = 0.f;
  }
  const float scale = 0.125f;  // 1/sqrt(64)

  for (int kt = 0; kt <= qt; ++kt) {
    const int s0 = kt * 64;
    // stage K transposed [d][s] and V natural [s][d]
#pragma unroll
    for (int dd = 0; dd < 16; dd += 4) {
      float4 kv = *(const float4*)(Kb + (size_t)(s0 + lr) * DH_ + lq * 16 + dd);
      Kt[lq * 16 + dd + 0][lr] = kv.x;
      Kt[lq * 16 + dd + 1][lr] = kv.y;
      Kt[lq * 16 + dd + 2][lr] = kv.z;
      Kt[lq * 16 + dd + 3][lr] = kv.w;
      *(float4*)&Vs[lr][lq * 16 + dd] =
          *(const float4*)(Vb + (size_t)(s0 + lr) * DH_ + lq * 16 + dd);
    }
    __syncthreads();

    // S = Q K^T (4x4 per thread)
    float s[4][4] = {};
#pragma unroll 8
    for (int d = 0; d < 64; ++d) {
      float4 a = *(const float4*)&Qt[d][ty * 4];
      float4 b = *(const float4*)&Kt[d][tx * 4];
      s[0][0] += a.x * b.x; s[0][1] += a.x * b.y; s[0][2] += a.x * b.z; s[0][3] += a.x * b.w;
      s[1][0] += a.y * b.x; s[1][1] += a.y * b.y; s[1][2] += a.y * b.z; s[1][3] += a.y * b.w;
      s[2][0] += a.z * b.x; s[2][1] += a.z * b.y; s[2][2] += a.z * b.z; s[2][3] += a.z * b.w;
      s[3][0] += a.w * b.x; s[3][1] += a.w * b.y; s[3][2] += a.w * b.z; s[3][3] += a.w * b.w;
    }

    // online softmax
    const bool diag = (kt == qt);
#pragma unroll
    for (int i = 0; i < 4; ++i) {
      const int qg = q0 + ty * 4 + i;
      float mx = -INFINITY;
#pragma unroll
      for (int j = 0; j < 4; ++j) {
        float sv = s[i][j] * scale;
        if (diag && (s0 + tx * 4 + j > qg)) sv = -INFINITY;
        s[i][j] = sv;
        mx = fmaxf(mx, sv);
      }
      mx = fmaxf(mx, __shfl_xor(mx, 1));
      mx = fmaxf(mx, __shfl_xor(mx, 2));
      mx = fmaxf(mx, __shfl_xor(mx, 4));
      mx = fmaxf(mx, __shfl_xor(mx, 8));
      const float mn   = fmaxf(m_i[i], mx);
      const float corr = __expf(m_i[i] - mn);   // first tile: exp(-inf)=0
      m_i[i] = mn;
      float rs = 0.f;
#pragma unroll
      for (int j = 0; j < 4; ++j) {
        float p = __expf(s[i][j] - mn);         // masked: exp(-inf)=0
        s[i][j] = p;
        rs += p;
      }
      rs += __shfl_xor(rs, 1);
      rs += __shfl_xor(rs, 2);
      rs += __shfl_xor(rs, 4);
      rs += __shfl_xor(rs, 8);
      l_i[i] = l_i[i] * corr + rs;
#pragma unroll
      for (int j = 0; j < 4; ++j) Oacc[i][j] *= corr;
    }

    // write P transposed [s][r]
#pragma unroll
    for (int i = 0; i < 4; ++i)
#pragma unroll
      for (int j = 0; j < 4; ++j) Pt[tx * 4 + j][ty * 4 + i] = s[i][j];
    __syncthreads();

    // O += P V
#pragma unroll 8
    for (int ss = 0; ss < 64; ++ss) {
      float4 a = *(const float4*)&Pt[ss][ty * 4];
      float4 b = *(const float4*)&Vs[ss][tx * 4];
      Oacc[0][0] += a.x * b.x; Oacc[0][1] += a.x * b.y; Oacc[0][2] += a.x * b.z; Oacc[0][3] += a.x * b.w;
      Oacc[1][0] += a.y * b.x; Oacc[1][1] += a.y * b.y; Oacc[1][2] += a.y * b.z; Oacc[1][3] += a.y * b.w;
      Oacc[2][0] += a.z * b.x; Oacc[2][1] += a.z * b.y; Oacc[2][2] += a.z * b.z; Oacc[2][3] += a.z * b.w;
      Oacc[3][0] += a.w * b.x; Oacc[3][1] += a.w * b.y; Oacc[3][2] += a.w * b.z; Oacc[3][3] += a.w * b.w;
    }
    __syncthreads();  // protect Kt/Vs/Pt for next iteration
  }

  const int bb = bh / H_, hh = bh - (bh / H_) * H_;
#pragma unroll
  for (int i = 0; i < 4; ++i) {
    const int t = q0 + ty * 4 + i;
    const float inv = 1.0f / l_i[i];
    float4 o = make_float4(Oacc[i][0] * inv, Oacc[i][1] * inv,
                           Oacc[i][2] * inv, Oacc[i][3] * inv);
    *(float4*)(o_ws + ((size_t)bb * T_ + t) * E_ + hh * DH_ + tx * 4) = o;
  }
}

// ---------------------------------------------------------------------------
// Output projection: out[m,n] = sum_k O[m,k] * Wp[k,n] + bp[n]
// grid.x = 12 n-tiles, grid.y = 64 m-tiles. 256 threads.
// ---------------------------------------------------------------------------
__global__ __launch_bounds__(256) void proj_gemm_k(
    const float* __restrict__ A, const float* __restrict__ Wp,
    const float* __restrict__ bp, float* __restrict__ out)
{
  __shared__ __align__(16) float As[16][68];
  __shared__ __align__(16) float Bs[16][64];

  const int n0 = blockIdx.x * 64;
  const int m0 = blockIdx.y * 64;

  const int tid = threadIdx.x;
  const int tx  = tid & 15, ty = tid >> 4;
  const int lr  = tid >> 2, lq = tid & 3;

  float acc[4][4] = {};

  for (int k0 = 0; k0 < E_; k0 += 16) {
    float4 av = *(const float4*)(A + (size_t)(m0 + lr) * E_ + k0 + lq * 4);
    As[lq * 4 + 0][lr] = av.x;
    As[lq * 4 + 1][lr] = av.y;
    As[lq * 4 + 2][lr] = av.z;
    As[lq * 4 + 3][lr] = av.w;
    *(float4*)&Bs[ty][tx * 4] =
        *(const float4*)(Wp + (size_t)(k0 + ty) * E_ + n0 + tx * 4);
    __syncthreads();
#pragma unroll
    for (int kk = 0; kk < 16; ++kk) {
      float4 a = *(const float4*)&As[kk][ty * 4];
      float4 b = *(const float4*)&Bs[kk][tx * 4];
      acc[0][0] += a.x * b.x; acc[0][1] += a.x * b.y; acc[0][2] += a.x * b.z; acc[0][3] += a.x * b.w;
      acc[1][0] += a.y * b.x; acc[1][1] += a.y * b.y; acc[1][2] += a.y * b.z; acc[1][3] += a.y * b.w;
      acc[2][0] += a.z * b.x; acc[2][1] += a.z * b.y; acc[2][2] += a.z * b.z; acc[2][3] += a.z * b.w;
      acc[3][0] += a.w * b.x; acc[3][1] += a.w * b.y; acc[3][2] += a.w * b.z; acc[3][3] += a.w * b.w;
    }
    __syncthreads();
  }

  const float4 bias = *(const float4*)(bp + n0 + tx * 4);
#pragma unroll
  for (int i = 0; i < 4; ++i) {
    float4 o = make_float4(acc[i][0] + bias.x, acc[i][1] + bias.y,
                           acc[i][2] + bias.z, acc[i][3] + bias.w);
    *(float4*)(out + (size_t)(m0 + ty * 4 + i) * E_ + n0 + tx * 4) = o;
  }
}

}  // namespace

extern "C" void kernel_launch(void* const* d_in, const int* in_sizes, int n_in,
                              void* d_out, int out_size, void* d_ws, size_t ws_size,
                              hipStream_t stream) {
  const float* x  = (const float*)d_in[0];
  const float* Wq = (const float*)d_in[1];
  const float* Wk = (const float*)d_in[2];
  const float* Wv = (const float*)d_in[3];
  const float* Wp = (const float*)d_in[4];
  const float* bp = (const float*)d_in[5];
  float* out = (float*)d_out;

  // workspace: Q, K, V in [b*H+h][t][64] layout, O in [b][t][768] layout
  const size_t per = (size_t)B_ * H_ * T_ * DH_;  // 3,145,728 floats each
  float* q_ws = (float*)d_ws;
  float* k_ws = q_ws + per;
  float* v_ws = k_ws + per;
  float* o_ws = v_ws + per;

  qkv_gemm_k<<<dim3(36, 64), 256, 0, stream>>>(x, Wq, Wk, Wv, q_ws, k_ws, v_ws);
  attn_k<<<dim3(32, 24), 256, 0, stream>>>(q_ws, k_ws, v_ws, o_ws);
  proj_gemm_k<<<dim3(12, 64), 256, 0, stream>>>(o_ws, Wp, bp, out);
}

// Round 2
// 370.317 us; speedup vs baseline: 1.8070x; 1.8070x over previous
//
#include <hip/hip_runtime.h>
#include <math.h>

namespace {

constexpr int E_  = 768;
constexpr int H_  = 12;
constexpr int DH_ = 64;
constexpr int T_  = 2048;
constexpr int B_  = 2;

typedef __attribute__((ext_vector_type(8))) short bf16x8;
typedef __attribute__((ext_vector_type(4))) float f32x4;

__device__ inline ushort f2bf(float f) {
  union { float f; unsigned u; } v; v.f = f;
  unsigned u = v.u + 0x7FFFu + ((v.u >> 16) & 1u);  // RNE
  return (ushort)(u >> 16);
}

// ---------------------------------------------------------------------------
// QKV projection (f32 compute, bf16 output): Y = x @ W[h] for W in {Wq,Wk,Wv}
// Q is pre-scaled by 1/sqrt(Dh). Output layout: ws[(b*H+h)][t][64] bf16.
// ---------------------------------------------------------------------------
__global__ __launch_bounds__(256) void qkv_gemm_k(
    const float* __restrict__ x, const float* __restrict__ Wq,
    const float* __restrict__ Wk, const float* __restrict__ Wv,
    ushort* __restrict__ q_ws, ushort* __restrict__ k_ws, ushort* __restrict__ v_ws)
{
  __shared__ __align__(16) float As[16][68];  // [k][m]
  __shared__ __align__(16) float Bs[16][64];  // [k][d]

  const int bx  = blockIdx.x;          // 0..35
  const int m0  = blockIdx.y * 64;
  const int mat = bx / H_;
  const int h   = bx - mat * H_;
  const float* W    = (mat == 0) ? Wq : (mat == 1) ? Wk : Wv;
  const float* Wh   = W + (size_t)h * E_ * DH_;
  ushort*      outw = (mat == 0) ? q_ws : (mat == 1) ? k_ws : v_ws;

  const int tid = threadIdx.x;
  const int tx  = tid & 15, ty = tid >> 4;
  const int lr  = tid >> 2, lq = tid & 3;

  float acc[4][4] = {};

  for (int k0 = 0; k0 < E_; k0 += 16) {
    float4 av = *(const float4*)(x + (size_t)(m0 + lr) * E_ + k0 + lq * 4);
    As[lq * 4 + 0][lr] = av.x;
    As[lq * 4 + 1][lr] = av.y;
    As[lq * 4 + 2][lr] = av.z;
    As[lq * 4 + 3][lr] = av.w;
    *(float4*)&Bs[ty][tx * 4] =
        *(const float4*)(Wh + (size_t)(k0 + ty) * DH_ + tx * 4);
    __syncthreads();
#pragma unroll
    for (int kk = 0; kk < 16; ++kk) {
      float4 a = *(const float4*)&As[kk][ty * 4];
      float4 b = *(const float4*)&Bs[kk][tx * 4];
      acc[0][0] += a.x * b.x; acc[0][1] += a.x * b.y; acc[0][2] += a.x * b.z; acc[0][3] += a.x * b.w;
      acc[1][0] += a.y * b.x; acc[1][1] += a.y * b.y; acc[1][2] += a.y * b.z; acc[1][3] += a.y * b.w;
      acc[2][0] += a.z * b.x; acc[2][1] += a.z * b.y; acc[2][2] += a.z * b.z; acc[2][3] += a.z * b.w;
      acc[3][0] += a.w * b.x; acc[3][1] += a.w * b.y; acc[3][2] += a.w * b.z; acc[3][3] += a.w * b.w;
    }
    __syncthreads();
  }

  const int b = m0 / T_;
  const float qs = (mat == 0) ? 0.125f : 1.0f;  // fold 1/sqrt(64) into Q
#pragma unroll
  for (int i = 0; i < 4; ++i) {
    const int t = m0 + ty * 4 + i - b * T_;
    ushort4 o;
    o.x = f2bf(acc[i][0] * qs); o.y = f2bf(acc[i][1] * qs);
    o.z = f2bf(acc[i][2] * qs); o.w = f2bf(acc[i][3] * qs);
    *(ushort4*)(outw + ((size_t)(b * H_ + h) * T_ + t) * DH_ + tx * 4) = o;
  }
}

// ---------------------------------------------------------------------------
// Causal flash attention, bf16 MFMA. grid.x = 32 q-tiles (descending),
// grid.y = 24 (b*H+h). 4 waves; wave w owns q-rows [w*16, w*16+16).
// S = Q K^T via mfma_f32_16x16x32_bf16; online softmax on C-layout regs;
// P transposed through per-wave LDS; O += P V via MFMA.
// ---------------------------------------------------------------------------
constexpr int LDK = 72;  // padded LDS row stride in bf16 elems (144 B)

__global__ __launch_bounds__(256) void attn_mfma_k(
    const ushort* __restrict__ q_ws, const ushort* __restrict__ k_ws,
    const ushort* __restrict__ v_ws, float* __restrict__ o_ws)
{
  __shared__ __align__(16) ushort Ks[64 * LDK];      // K tile, [s][d]
  __shared__ __align__(16) ushort Vt[64 * LDK];      // V tile transposed, [d][s]
  __shared__ __align__(16) ushort Pl[4][16 * LDK];   // per-wave P, [r][s]

  const int qt = (int)gridDim.x - 1 - blockIdx.x;    // long blocks first
  const int bh = blockIdx.y;
  const int q0 = qt * 64;
  const ushort* Qb = q_ws + (size_t)bh * T_ * DH_;
  const ushort* Kb = k_ws + (size_t)bh * T_ * DH_;
  const ushort* Vb = v_ws + (size_t)bh * T_ * DH_;

  const int tid  = threadIdx.x;
  const int w    = tid >> 6;
  const int l    = tid & 63;
  const int lrow = l & 15;   // A/B fragment row/col index
  const int lk   = l >> 4;   // k-group (and C-row group)

  // Q fragments in registers (row = lrow, k = lk*8 + j [+32])
  const ushort* Qrow = Qb + (size_t)(q0 + w * 16 + lrow) * DH_;
  const bf16x8 qa0 = *(const bf16x8*)(Qrow + lk * 8);
  const bf16x8 qa1 = *(const bf16x8*)(Qrow + lk * 8 + 32);

  float m_i[4], l_i[4];
  f32x4 oc[4] = {};
#pragma unroll
  for (int i = 0; i < 4; ++i) { m_i[i] = -INFINITY; l_i[i] = 0.f; }

  for (int kt = 0; kt <= qt; ++kt) {
    const int s0 = kt * 64;

    // ---- stage K [s][d] (coalesced 16B copies) ----
#pragma unroll
    for (int it = 0; it < 2; ++it) {
      const int c = tid + it * 256;            // 512 chunks of 8 bf16
      const int s = c >> 3, dc = c & 7;
      *(bf16x8*)&Ks[s * LDK + dc * 8] =
          *(const bf16x8*)(Kb + (size_t)(s0 + s) * DH_ + dc * 8);
    }
    // ---- stage V transposed [d][s] (lane = s → conflict-free-ish writes) ----
#pragma unroll
    for (int it = 0; it < 2; ++it) {
      const int dc = w + it * 4;               // 0..7
      bf16x8 vv = *(const bf16x8*)(Vb + (size_t)(s0 + l) * DH_ + dc * 8);
#pragma unroll
      for (int j = 0; j < 8; ++j)
        Vt[(dc * 8 + j) * LDK + l] = (ushort)vv[j];
    }
    __syncthreads();

    // ---- S = Q K^T : 16x64 per wave ----
    f32x4 sacc[4];
#pragma unroll
    for (int ct = 0; ct < 4; ++ct) {
      const bf16x8 kb0 = *(const bf16x8*)&Ks[(ct * 16 + lrow) * LDK + lk * 8];
      const bf16x8 kb1 = *(const bf16x8*)&Ks[(ct * 16 + lrow) * LDK + lk * 8 + 32];
      f32x4 z = {0.f, 0.f, 0.f, 0.f};
      z = __builtin_amdgcn_mfma_f32_16x16x32_bf16(qa0, kb0, z, 0, 0, 0);
      sacc[ct] = __builtin_amdgcn_mfma_f32_16x16x32_bf16(qa1, kb1, z, 0, 0, 0);
    }

    // ---- online softmax (row = lk*4+i, col = ct*16+lrow) ----
    const bool diag = (kt == qt);
    float corr_a[4];
#pragma unroll
    for (int i = 0; i < 4; ++i) {
      const int qg = q0 + w * 16 + lk * 4 + i;
      float mx = m_i[i];
#pragma unroll
      for (int ct = 0; ct < 4; ++ct) {
        float sv = sacc[ct][i];
        if (diag && (s0 + ct * 16 + lrow > qg)) sv = -INFINITY;
        sacc[ct][i] = sv;
        mx = fmaxf(mx, sv);
      }
      mx = fmaxf(mx, __shfl_xor(mx, 1));
      mx = fmaxf(mx, __shfl_xor(mx, 2));
      mx = fmaxf(mx, __shfl_xor(mx, 4));
      mx = fmaxf(mx, __shfl_xor(mx, 8));
      corr_a[i] = __expf(m_i[i] - mx);   // first tile: exp(-inf)=0
      m_i[i] = mx;
      float rs = 0.f;
#pragma unroll
      for (int ct = 0; ct < 4; ++ct) {
        const float p = __expf(sacc[ct][i] - mx);
        sacc[ct][i] = p;
        rs += p;
      }
      rs += __shfl_xor(rs, 1);
      rs += __shfl_xor(rs, 2);
      rs += __shfl_xor(rs, 4);
      rs += __shfl_xor(rs, 8);
      l_i[i] = l_i[i] * corr_a[i] + rs;
    }
#pragma unroll
    for (int ct = 0; ct < 4; ++ct)
#pragma unroll
      for (int i = 0; i < 4; ++i) oc[ct][i] *= corr_a[i];

    // ---- P -> LDS (bf16, transposed via C-layout write / A-layout read) ----
#pragma unroll
    for (int ct = 0; ct < 4; ++ct)
#pragma unroll
      for (int i = 0; i < 4; ++i)
        Pl[w][(lk * 4 + i) * LDK + ct * 16 + lrow] = f2bf(sacc[ct][i]);

    // ---- O += P V ----
    const bf16x8 pa0 = *(const bf16x8*)&Pl[w][lrow * LDK + lk * 8];
    const bf16x8 pa1 = *(const bf16x8*)&Pl[w][lrow * LDK + lk * 8 + 32];
#pragma unroll
    for (int ct = 0; ct < 4; ++ct) {
      const bf16x8 vb0 = *(const bf16x8*)&Vt[(ct * 16 + lrow) * LDK + lk * 8];
      const bf16x8 vb1 = *(const bf16x8*)&Vt[(ct * 16 + lrow) * LDK + lk * 8 + 32];
      oc[ct] = __builtin_amdgcn_mfma_f32_16x16x32_bf16(pa0, vb0, oc[ct], 0, 0, 0);
      oc[ct] = __builtin_amdgcn_mfma_f32_16x16x32_bf16(pa1, vb1, oc[ct], 0, 0, 0);
    }
    __syncthreads();   // protect Ks/Vt for next k-tile
  }

  // ---- epilogue: normalize, write concat-heads f32 ----
  const int bb = bh / H_, hh = bh - (bh / H_) * H_;
#pragma unroll
  for (int i = 0; i < 4; ++i) {
    const float inv = 1.0f / l_i[i];
    const int t = q0 + w * 16 + lk * 4 + i;
    float* orow = o_ws + ((size_t)bb * T_ + t) * E_ + hh * DH_;
#pragma unroll
    for (int ct = 0; ct < 4; ++ct)
      orow[ct * 16 + lrow] = oc[ct][i] * inv;
  }
}

// ---------------------------------------------------------------------------
// Output projection (f32): out = O @ Wp + bp
// ---------------------------------------------------------------------------
__global__ __launch_bounds__(256) void proj_gemm_k(
    const float* __restrict__ A, const float* __restrict__ Wp,
    const float* __restrict__ bp, float* __restrict__ out)
{
  __shared__ __align__(16) float As[16][68];
  __shared__ __align__(16) float Bs[16][64];

  const int n0 = blockIdx.x * 64;
  const int m0 = blockIdx.y * 64;

  const int tid = threadIdx.x;
  const int tx  = tid & 15, ty = tid >> 4;
  const int lr  = tid >> 2, lq = tid & 3;

  float acc[4][4] = {};

  for (int k0 = 0; k0 < E_; k0 += 16) {
    float4 av = *(const float4*)(A + (size_t)(m0 + lr) * E_ + k0 + lq * 4);
    As[lq * 4 + 0][lr] = av.x;
    As[lq * 4 + 1][lr] = av.y;
    As[lq * 4 + 2][lr] = av.z;
    As[lq * 4 + 3][lr] = av.w;
    *(float4*)&Bs[ty][tx * 4] =
        *(const float4*)(Wp + (size_t)(k0 + ty) * E_ + n0 + tx * 4);
    __syncthreads();
#pragma unroll
    for (int kk = 0; kk < 16; ++kk) {
      float4 a = *(const float4*)&As[kk][ty * 4];
      float4 b = *(const float4*)&Bs[kk][tx * 4];
      acc[0][0] += a.x * b.x; acc[0][1] += a.x * b.y; acc[0][2] += a.x * b.z; acc[0][3] += a.x * b.w;
      acc[1][0] += a.y * b.x; acc[1][1] += a.y * b.y; acc[1][2] += a.y * b.z; acc[1][3] += a.y * b.w;
      acc[2][0] += a.z * b.x; acc[2][1] += a.z * b.y; acc[2][2] += a.z * b.z; acc[2][3] += a.z * b.w;
      acc[3][0] += a.w * b.x; acc[3][1] += a.w * b.y; acc[3][2] += a.w * b.z; acc[3][3] += a.w * b.w;
    }
    __syncthreads();
  }

  const float4 bias = *(const float4*)(bp + n0 + tx * 4);
#pragma unroll
  for (int i = 0; i < 4; ++i) {
    float4 o = make_float4(acc[i][0] + bias.x, acc[i][1] + bias.y,
                           acc[i][2] + bias.z, acc[i][3] + bias.w);
    *(float4*)(out + (size_t)(m0 + ty * 4 + i) * E_ + n0 + tx * 4) = o;
  }
}

}  // namespace

extern "C" void kernel_launch(void* const* d_in, const int* in_sizes, int n_in,
                              void* d_out, int out_size, void* d_ws, size_t ws_size,
                              hipStream_t stream) {
  const float* x  = (const float*)d_in[0];
  const float* Wq = (const float*)d_in[1];
  const float* Wk = (const float*)d_in[2];
  const float* Wv = (const float*)d_in[3];
  const float* Wp = (const float*)d_in[4];
  const float* bp = (const float*)d_in[5];
  float* out = (float*)d_out;

  // workspace: Q,K,V bf16 in [b*H+h][t][64], O f32 in [b][t][768]
  const size_t per = (size_t)B_ * H_ * T_ * DH_;  // 3,145,728 elems
  ushort* q_ws = (ushort*)d_ws;
  ushort* k_ws = q_ws + per;
  ushort* v_ws = k_ws + per;
  float*  o_ws = (float*)(v_ws + per);

  qkv_gemm_k<<<dim3(36, 64), 256, 0, stream>>>(x, Wq, Wk, Wv, q_ws, k_ws, v_ws);
  attn_mfma_k<<<dim3(32, 24), 256, 0, stream>>>(q_ws, k_ws, v_ws, o_ws);
  proj_gemm_k<<<dim3(12, 64), 256, 0, stream>>>(o_ws, Wp, bp, out);
}

// Round 3
// 178.306 us; speedup vs baseline: 3.7529x; 2.0769x over previous
//
#include <hip/hip_runtime.h>
#include <math.h>

namespace {

constexpr int E_  = 768;
constexpr int H_  = 12;
constexpr int DH_ = 64;
constexpr int T_  = 2048;
constexpr int B_  = 2;
constexpr int M_  = B_ * T_;  // 4096

typedef __attribute__((ext_vector_type(8))) short bf16x8;
typedef __attribute__((ext_vector_type(4))) float f32x4;

__device__ inline ushort f2bf(float f) {
  union { float f; unsigned u; } v; v.f = f;
  unsigned u = v.u + 0x7FFFu + ((v.u >> 16) & 1u);  // RNE
  return (ushort)(u >> 16);
}

// ---------------------------------------------------------------------------
// x f32 -> bf16, elementwise (8 per thread)
// ---------------------------------------------------------------------------
__global__ __launch_bounds__(256) void convert_x_k(
    const float* __restrict__ x, ushort* __restrict__ xb)
{
  const size_t i = ((size_t)blockIdx.x * 256 + threadIdx.x) * 8;
  float4 a = *(const float4*)(x + i);
  float4 b = *(const float4*)(x + i + 4);
  ushort o[8] = {f2bf(a.x), f2bf(a.y), f2bf(a.z), f2bf(a.w),
                 f2bf(b.x), f2bf(b.y), f2bf(b.z), f2bf(b.w)};
  *(bf16x8*)(xb + i) = *(bf16x8*)o;
}

// ---------------------------------------------------------------------------
// Weight transpose + convert: W [K][N] f32 -> Wt [N][K] bf16 (k-contiguous).
// blocks 0..431: Wq/Wk/Wv per (mat,head,ktile); 432..575: Wp 12x12 tiles.
// ---------------------------------------------------------------------------
__global__ __launch_bounds__(256) void transpose_w_k(
    const float* __restrict__ Wq, const float* __restrict__ Wk,
    const float* __restrict__ Wv, const float* __restrict__ Wp,
    ushort* __restrict__ Wt, ushort* __restrict__ Wpt)
{
  __shared__ float tile[64][65];
  const int bid = blockIdx.x;
  const int tid = threadIdx.x;
  const int tr = tid >> 4, tc = tid & 15;

  const float* src; ushort* dst;
  int k0, n0, sN, dK;
  if (bid < 432) {
    const int mat = bid / 144, rem = bid % 144;
    const int h = rem / 12, ktile = rem % 12;
    const float* W = (mat == 0) ? Wq : (mat == 1) ? Wk : Wv;
    src = W + (size_t)h * E_ * DH_;                 // [768][64]
    dst = Wt + (size_t)(mat * H_ + h) * DH_ * E_;   // [64][768]
    k0 = ktile * 64; n0 = 0; sN = DH_; dK = E_;
  } else {
    const int rem = bid - 432;
    src = Wp;                                        // [768][768]
    dst = Wpt;                                       // [768][768] transposed
    k0 = (rem / 12) * 64; n0 = (rem % 12) * 64; sN = E_; dK = E_;
  }

#pragma unroll
  for (int rr = 0; rr < 64; rr += 16) {
    float4 v = *(const float4*)(src + (size_t)(k0 + tr + rr) * sN + n0 + tc * 4);
    tile[tr + rr][tc * 4 + 0] = v.x;
    tile[tr + rr][tc * 4 + 1] = v.y;
    tile[tr + rr][tc * 4 + 2] = v.z;
    tile[tr + rr][tc * 4 + 3] = v.w;
  }
  __syncthreads();
#pragma unroll
  for (int rr = 0; rr < 64; rr += 16) {
    const int n = tr + rr;
    ushort4 o;
    o.x = f2bf(tile[tc * 4 + 0][n]);
    o.y = f2bf(tile[tc * 4 + 1][n]);
    o.z = f2bf(tile[tc * 4 + 2][n]);
    o.w = f2bf(tile[tc * 4 + 3][n]);
    *(ushort4*)(dst + (size_t)(n0 + n) * dK + k0 + tc * 4) = o;
  }
}

// ---------------------------------------------------------------------------
// QKV MFMA GEMM: Y[h] = xb @ W[h]  (bf16 in, bf16 out, f32 acc)
// grid.x = 36 (mat*12+h), grid.y = 32 (m-tiles of 128). 4 waves, 32x64/wave.
// Q pre-scaled by 1/8. Output ws[(b*H+h)][t][64] bf16.
// ---------------------------------------------------------------------------
constexpr int GLD = 72;  // padded LDS row stride (bf16 elems, 144 B)

__global__ __launch_bounds__(256) void qkv_mfma_k(
    const ushort* __restrict__ xb, const ushort* __restrict__ Wt,
    ushort* __restrict__ q_ws, ushort* __restrict__ k_ws, ushort* __restrict__ v_ws)
{
  __shared__ __align__(16) ushort As[128 * GLD];  // [m][k]
  __shared__ __align__(16) ushort Bs[64 * GLD];   // [n][k]

  const int bx  = blockIdx.x;
  const int m0  = blockIdx.y * 128;
  const int mat = bx / H_;
  const int h   = bx - mat * H_;
  const ushort* Wh   = Wt + (size_t)bx * DH_ * E_;
  ushort*       outw = (mat == 0) ? q_ws : (mat == 1) ? k_ws : v_ws;

  const int tid  = threadIdx.x;
  const int w    = tid >> 6, l = tid & 63;
  const int lrow = l & 15, lk = l >> 4;

  f32x4 acc[2][4] = {};

  for (int k0 = 0; k0 < E_; k0 += 64) {
    // stage A 128x64 (1024 16B-chunks / 4 iters)
#pragma unroll
    for (int it = 0; it < 4; ++it) {
      const int c = tid + it * 256;
      const int r = c >> 3, sub = c & 7;
      *(bf16x8*)&As[r * GLD + sub * 8] =
          *(const bf16x8*)(xb + (size_t)(m0 + r) * E_ + k0 + sub * 8);
    }
    // stage B 64x64 (512 chunks / 2 iters)
#pragma unroll
    for (int it = 0; it < 2; ++it) {
      const int c = tid + it * 256;
      const int r = c >> 3, sub = c & 7;
      *(bf16x8*)&Bs[r * GLD + sub * 8] =
          *(const bf16x8*)(Wh + (size_t)r * E_ + k0 + sub * 8);
    }
    __syncthreads();

#pragma unroll
    for (int kk = 0; kk < 2; ++kk) {
      const bf16x8 a0 = *(const bf16x8*)&As[(w * 32 + lrow) * GLD + kk * 32 + lk * 8];
      const bf16x8 a1 = *(const bf16x8*)&As[(w * 32 + 16 + lrow) * GLD + kk * 32 + lk * 8];
#pragma unroll
      for (int ni = 0; ni < 4; ++ni) {
        const bf16x8 b = *(const bf16x8*)&Bs[(ni * 16 + lrow) * GLD + kk * 32 + lk * 8];
        acc[0][ni] = __builtin_amdgcn_mfma_f32_16x16x32_bf16(a0, b, acc[0][ni], 0, 0, 0);
        acc[1][ni] = __builtin_amdgcn_mfma_f32_16x16x32_bf16(a1, b, acc[1][ni], 0, 0, 0);
      }
    }
    __syncthreads();
  }

  const int b  = m0 / T_;  // 128-tiles never straddle batch boundary
  const int bh = b * H_ + h;
  const float qs = (mat == 0) ? 0.125f : 1.0f;
#pragma unroll
  for (int mi = 0; mi < 2; ++mi)
#pragma unroll
    for (int i = 0; i < 4; ++i) {
      const int t = m0 + w * 32 + mi * 16 + lk * 4 + i - b * T_;
      ushort* orow = outw + ((size_t)bh * T_ + t) * DH_;
#pragma unroll
      for (int ni = 0; ni < 4; ++ni)
        orow[ni * 16 + lrow] = f2bf(acc[mi][ni][i] * qs);
    }
}

// ---------------------------------------------------------------------------
// Causal flash attention, bf16 MFMA (unchanged from R2 except bf16 output).
// ---------------------------------------------------------------------------
constexpr int LDK = 72;

__global__ __launch_bounds__(256) void attn_mfma_k(
    const ushort* __restrict__ q_ws, const ushort* __restrict__ k_ws,
    const ushort* __restrict__ v_ws, ushort* __restrict__ o_ws)
{
  __shared__ __align__(16) ushort Ks[64 * LDK];
  __shared__ __align__(16) ushort Vt[64 * LDK];
  __shared__ __align__(16) ushort Pl[4][16 * LDK];

  const int qt = (int)gridDim.x - 1 - blockIdx.x;
  const int bh = blockIdx.y;
  const int q0 = qt * 64;
  const ushort* Qb = q_ws + (size_t)bh * T_ * DH_;
  const ushort* Kb = k_ws + (size_t)bh * T_ * DH_;
  const ushort* Vb = v_ws + (size_t)bh * T_ * DH_;

  const int tid  = threadIdx.x;
  const int w    = tid >> 6;
  const int l    = tid & 63;
  const int lrow = l & 15;
  const int lk   = l >> 4;

  const ushort* Qrow = Qb + (size_t)(q0 + w * 16 + lrow) * DH_;
  const bf16x8 qa0 = *(const bf16x8*)(Qrow + lk * 8);
  const bf16x8 qa1 = *(const bf16x8*)(Qrow + lk * 8 + 32);

  float m_i[4], l_i[4];
  f32x4 oc[4] = {};
#pragma unroll
  for (int i = 0; i < 4; ++i) { m_i[i] = -INFINITY; l_i[i] = 0.f; }

  for (int kt = 0; kt <= qt; ++kt) {
    const int s0 = kt * 64;
#pragma unroll
    for (int it = 0; it < 2; ++it) {
      const int c = tid + it * 256;
      const int s = c >> 3, dc = c & 7;
      *(bf16x8*)&Ks[s * LDK + dc * 8] =
          *(const bf16x8*)(Kb + (size_t)(s0 + s) * DH_ + dc * 8);
    }
#pragma unroll
    for (int it = 0; it < 2; ++it) {
      const int dc = w + it * 4;
      bf16x8 vv = *(const bf16x8*)(Vb + (size_t)(s0 + l) * DH_ + dc * 8);
#pragma unroll
      for (int j = 0; j < 8; ++j)
        Vt[(dc * 8 + j) * LDK + l] = (ushort)vv[j];
    }
    __syncthreads();

    f32x4 sacc[4];
#pragma unroll
    for (int ct = 0; ct < 4; ++ct) {
      const bf16x8 kb0 = *(const bf16x8*)&Ks[(ct * 16 + lrow) * LDK + lk * 8];
      const bf16x8 kb1 = *(const bf16x8*)&Ks[(ct * 16 + lrow) * LDK + lk * 8 + 32];
      f32x4 z = {0.f, 0.f, 0.f, 0.f};
      z = __builtin_amdgcn_mfma_f32_16x16x32_bf16(qa0, kb0, z, 0, 0, 0);
      sacc[ct] = __builtin_amdgcn_mfma_f32_16x16x32_bf16(qa1, kb1, z, 0, 0, 0);
    }

    const bool diag = (kt == qt);
    float corr_a[4];
#pragma unroll
    for (int i = 0; i < 4; ++i) {
      const int qg = q0 + w * 16 + lk * 4 + i;
      float mx = m_i[i];
#pragma unroll
      for (int ct = 0; ct < 4; ++ct) {
        float sv = sacc[ct][i];
        if (diag && (s0 + ct * 16 + lrow > qg)) sv = -INFINITY;
        sacc[ct][i] = sv;
        mx = fmaxf(mx, sv);
      }
      mx = fmaxf(mx, __shfl_xor(mx, 1));
      mx = fmaxf(mx, __shfl_xor(mx, 2));
      mx = fmaxf(mx, __shfl_xor(mx, 4));
      mx = fmaxf(mx, __shfl_xor(mx, 8));
      corr_a[i] = __expf(m_i[i] - mx);
      m_i[i] = mx;
      float rs = 0.f;
#pragma unroll
      for (int ct = 0; ct < 4; ++ct) {
        const float p = __expf(sacc[ct][i] - mx);
        sacc[ct][i] = p;
        rs += p;
      }
      rs += __shfl_xor(rs, 1);
      rs += __shfl_xor(rs, 2);
      rs += __shfl_xor(rs, 4);
      rs += __shfl_xor(rs, 8);
      l_i[i] = l_i[i] * corr_a[i] + rs;
    }
#pragma unroll
    for (int ct = 0; ct < 4; ++ct)
#pragma unroll
      for (int i = 0; i < 4; ++i) oc[ct][i] *= corr_a[i];

#pragma unroll
    for (int ct = 0; ct < 4; ++ct)
#pragma unroll
      for (int i = 0; i < 4; ++i)
        Pl[w][(lk * 4 + i) * LDK + ct * 16 + lrow] = f2bf(sacc[ct][i]);

    const bf16x8 pa0 = *(const bf16x8*)&Pl[w][lrow * LDK + lk * 8];
    const bf16x8 pa1 = *(const bf16x8*)&Pl[w][lrow * LDK + lk * 8 + 32];
#pragma unroll
    for (int ct = 0; ct < 4; ++ct) {
      const bf16x8 vb0 = *(const bf16x8*)&Vt[(ct * 16 + lrow) * LDK + lk * 8];
      const bf16x8 vb1 = *(const bf16x8*)&Vt[(ct * 16 + lrow) * LDK + lk * 8 + 32];
      oc[ct] = __builtin_amdgcn_mfma_f32_16x16x32_bf16(pa0, vb0, oc[ct], 0, 0, 0);
      oc[ct] = __builtin_amdgcn_mfma_f32_16x16x32_bf16(pa1, vb1, oc[ct], 0, 0, 0);
    }
    __syncthreads();
  }

  const int bb = bh / H_, hh = bh - (bh / H_) * H_;
#pragma unroll
  for (int i = 0; i < 4; ++i) {
    const float inv = 1.0f / l_i[i];
    const int t = q0 + w * 16 + lk * 4 + i;
    ushort* orow = o_ws + ((size_t)bb * T_ + t) * E_ + hh * DH_;
#pragma unroll
    for (int ct = 0; ct < 4; ++ct)
      orow[ct * 16 + lrow] = f2bf(oc[ct][i] * inv);
  }
}

// ---------------------------------------------------------------------------
// Out-proj MFMA GEMM: out = ob @ Wp + bp  (bf16 in, f32 out)
// grid.x = 12 n-tiles, grid.y = 32 m-tiles of 128. 4 waves, 32x64/wave.
// ---------------------------------------------------------------------------
__global__ __launch_bounds__(256) void proj_mfma_k(
    const ushort* __restrict__ ob, const ushort* __restrict__ Wpt,
    const float* __restrict__ bp, float* __restrict__ out)
{
  __shared__ __align__(16) ushort As[128 * GLD];
  __shared__ __align__(16) ushort Bs[64 * GLD];

  const int n0 = blockIdx.x * 64;
  const int m0 = blockIdx.y * 128;

  const int tid  = threadIdx.x;
  const int w    = tid >> 6, l = tid & 63;
  const int lrow = l & 15, lk = l >> 4;

  f32x4 acc[2][4] = {};

  for (int k0 = 0; k0 < E_; k0 += 64) {
#pragma unroll
    for (int it = 0; it < 4; ++it) {
      const int c = tid + it * 256;
      const int r = c >> 3, sub = c & 7;
      *(bf16x8*)&As[r * GLD + sub * 8] =
          *(const bf16x8*)(ob + (size_t)(m0 + r) * E_ + k0 + sub * 8);
    }
#pragma unroll
    for (int it = 0; it < 2; ++it) {
      const int c = tid + it * 256;
      const int r = c >> 3, sub = c & 7;
      *(bf16x8*)&Bs[r * GLD + sub * 8] =
          *(const bf16x8*)(Wpt + (size_t)(n0 + r) * E_ + k0 + sub * 8);
    }
    __syncthreads();

#pragma unroll
    for (int kk = 0; kk < 2; ++kk) {
      const bf16x8 a0 = *(const bf16x8*)&As[(w * 32 + lrow) * GLD + kk * 32 + lk * 8];
      const bf16x8 a1 = *(const bf16x8*)&As[(w * 32 + 16 + lrow) * GLD + kk * 32 + lk * 8];
#pragma unroll
      for (int ni = 0; ni < 4; ++ni) {
        const bf16x8 b = *(const bf16x8*)&Bs[(ni * 16 + lrow) * GLD + kk * 32 + lk * 8];
        acc[0][ni] = __builtin_amdgcn_mfma_f32_16x16x32_bf16(a0, b, acc[0][ni], 0, 0, 0);
        acc[1][ni] = __builtin_amdgcn_mfma_f32_16x16x32_bf16(a1, b, acc[1][ni], 0, 0, 0);
      }
    }
    __syncthreads();
  }

  float bias[4];
#pragma unroll
  for (int ni = 0; ni < 4; ++ni) bias[ni] = bp[n0 + ni * 16 + lrow];

#pragma unroll
  for (int mi = 0; mi < 2; ++mi)
#pragma unroll
    for (int i = 0; i < 4; ++i) {
      const int m = m0 + w * 32 + mi * 16 + lk * 4 + i;
      float* orow = out + (size_t)m * E_ + n0;
#pragma unroll
      for (int ni = 0; ni < 4; ++ni)
        orow[ni * 16 + lrow] = acc[mi][ni][i] + bias[ni];
    }
}

}  // namespace

extern "C" void kernel_launch(void* const* d_in, const int* in_sizes, int n_in,
                              void* d_out, int out_size, void* d_ws, size_t ws_size,
                              hipStream_t stream) {
  const float* x  = (const float*)d_in[0];
  const float* Wq = (const float*)d_in[1];
  const float* Wk = (const float*)d_in[2];
  const float* Wv = (const float*)d_in[3];
  const float* Wp = (const float*)d_in[4];
  const float* bp = (const float*)d_in[5];
  float* out = (float*)d_out;

  const size_t nx  = (size_t)M_ * E_;            // 3,145,728
  const size_t nwt = (size_t)3 * H_ * DH_ * E_;  // 1,769,472
  const size_t nwp = (size_t)E_ * E_;            // 589,824
  const size_t per = (size_t)B_ * H_ * T_ * DH_; // 3,145,728

  ushort* xb   = (ushort*)d_ws;
  ushort* Wt   = xb + nx;
  ushort* Wpt  = Wt + nwt;
  ushort* q_ws = Wpt + nwp;
  ushort* k_ws = q_ws + per;
  ushort* v_ws = k_ws + per;
  ushort* o_b  = v_ws + per;

  convert_x_k<<<dim3((int)(nx / (256 * 8))), 256, 0, stream>>>(x, xb);
  transpose_w_k<<<dim3(576), 256, 0, stream>>>(Wq, Wk, Wv, Wp, Wt, Wpt);
  qkv_mfma_k<<<dim3(36, 32), 256, 0, stream>>>(xb, Wt, q_ws, k_ws, v_ws);
  attn_mfma_k<<<dim3(32, 24), 256, 0, stream>>>(q_ws, k_ws, v_ws, o_b);
  proj_mfma_k<<<dim3(12, 32), 256, 0, stream>>>(o_b, Wpt, bp, out);
}

// Round 4
// 118.155 us; speedup vs baseline: 5.6635x; 1.5091x over previous
//
#include <hip/hip_runtime.h>
#include <math.h>

namespace {

constexpr int E_  = 768;
constexpr int H_  = 12;
constexpr int DH_ = 64;
constexpr int T_  = 2048;
constexpr int B_  = 2;
constexpr int M_  = B_ * T_;  // 4096

typedef __attribute__((ext_vector_type(8))) short bf16x8;
typedef __attribute__((ext_vector_type(4))) float f32x4;

__device__ inline ushort f2bf(float f) {
  union { float f; unsigned u; } v; v.f = f;
  unsigned u = v.u + 0x7FFFu + ((v.u >> 16) & 1u);  // RNE
  return (ushort)(u >> 16);
}

// ---------------------------------------------------------------------------
// x f32 -> bf16, elementwise (8 per thread)
// ---------------------------------------------------------------------------
__global__ __launch_bounds__(256) void convert_x_k(
    const float* __restrict__ x, ushort* __restrict__ xb)
{
  const size_t i = ((size_t)blockIdx.x * 256 + threadIdx.x) * 8;
  float4 a = *(const float4*)(x + i);
  float4 b = *(const float4*)(x + i + 4);
  ushort o[8] = {f2bf(a.x), f2bf(a.y), f2bf(a.z), f2bf(a.w),
                 f2bf(b.x), f2bf(b.y), f2bf(b.z), f2bf(b.w)};
  *(bf16x8*)(xb + i) = *(bf16x8*)o;
}

// ---------------------------------------------------------------------------
// Weight transpose + convert: W [K][N] f32 -> Wt [N][K] bf16 (k-contiguous).
// ---------------------------------------------------------------------------
__global__ __launch_bounds__(256) void transpose_w_k(
    const float* __restrict__ Wq, const float* __restrict__ Wk,
    const float* __restrict__ Wv, const float* __restrict__ Wp,
    ushort* __restrict__ Wt, ushort* __restrict__ Wpt)
{
  __shared__ float tile[64][65];
  const int bid = blockIdx.x;
  const int tid = threadIdx.x;
  const int tr = tid >> 4, tc = tid & 15;

  const float* src; ushort* dst;
  int k0, n0, sN, dK;
  if (bid < 432) {
    const int mat = bid / 144, rem = bid % 144;
    const int h = rem / 12, ktile = rem % 12;
    const float* W = (mat == 0) ? Wq : (mat == 1) ? Wk : Wv;
    src = W + (size_t)h * E_ * DH_;
    dst = Wt + (size_t)(mat * H_ + h) * DH_ * E_;
    k0 = ktile * 64; n0 = 0; sN = DH_; dK = E_;
  } else {
    const int rem = bid - 432;
    src = Wp;
    dst = Wpt;
    k0 = (rem / 12) * 64; n0 = (rem % 12) * 64; sN = E_; dK = E_;
  }

#pragma unroll
  for (int rr = 0; rr < 64; rr += 16) {
    float4 v = *(const float4*)(src + (size_t)(k0 + tr + rr) * sN + n0 + tc * 4);
    tile[tr + rr][tc * 4 + 0] = v.x;
    tile[tr + rr][tc * 4 + 1] = v.y;
    tile[tr + rr][tc * 4 + 2] = v.z;
    tile[tr + rr][tc * 4 + 3] = v.w;
  }
  __syncthreads();
#pragma unroll
  for (int rr = 0; rr < 64; rr += 16) {
    const int n = tr + rr;
    ushort4 o;
    o.x = f2bf(tile[tc * 4 + 0][n]);
    o.y = f2bf(tile[tc * 4 + 1][n]);
    o.z = f2bf(tile[tc * 4 + 2][n]);
    o.w = f2bf(tile[tc * 4 + 3][n]);
    *(ushort4*)(dst + (size_t)(n0 + n) * dK + k0 + tc * 4) = o;
  }
}

// ---------------------------------------------------------------------------
// QKV MFMA GEMM. Q pre-scaled by 0.125*log2(e) (exp2-domain softmax).
// Q,K -> ws[(b*H+h)][t][64]; V -> TRANSPOSED vt_ws[(b*H+h)][d][t] via LDS bounce.
// ---------------------------------------------------------------------------
constexpr int GLD = 72;   // padded LDS row stride (bf16 elems)
constexpr int TDS = 136;  // V-transpose bounce row stride (16B-aligned rows)

__global__ __launch_bounds__(256) void qkv_mfma_k(
    const ushort* __restrict__ xb, const ushort* __restrict__ Wt,
    ushort* __restrict__ q_ws, ushort* __restrict__ k_ws, ushort* __restrict__ vt_ws)
{
  __shared__ __align__(16) ushort As[128 * GLD];  // [m][k]
  __shared__ __align__(16) ushort Bs[64 * GLD];   // [n][k]

  const int bx  = blockIdx.x;
  const int m0  = blockIdx.y * 128;
  const int mat = bx / H_;
  const int h   = bx - mat * H_;
  const ushort* Wh = Wt + (size_t)bx * DH_ * E_;

  const int tid  = threadIdx.x;
  const int w    = tid >> 6, l = tid & 63;
  const int lrow = l & 15, lk = l >> 4;

  f32x4 acc[2][4] = {};

  for (int k0 = 0; k0 < E_; k0 += 64) {
#pragma unroll
    for (int it = 0; it < 4; ++it) {
      const int c = tid + it * 256;
      const int r = c >> 3, sub = c & 7;
      *(bf16x8*)&As[r * GLD + sub * 8] =
          *(const bf16x8*)(xb + (size_t)(m0 + r) * E_ + k0 + sub * 8);
    }
#pragma unroll
    for (int it = 0; it < 2; ++it) {
      const int c = tid + it * 256;
      const int r = c >> 3, sub = c & 7;
      *(bf16x8*)&Bs[r * GLD + sub * 8] =
          *(const bf16x8*)(Wh + (size_t)r * E_ + k0 + sub * 8);
    }
    __syncthreads();

#pragma unroll
    for (int kk = 0; kk < 2; ++kk) {
      const bf16x8 a0 = *(const bf16x8*)&As[(w * 32 + lrow) * GLD + kk * 32 + lk * 8];
      const bf16x8 a1 = *(const bf16x8*)&As[(w * 32 + 16 + lrow) * GLD + kk * 32 + lk * 8];
#pragma unroll
      for (int ni = 0; ni < 4; ++ni) {
        const bf16x8 b = *(const bf16x8*)&Bs[(ni * 16 + lrow) * GLD + kk * 32 + lk * 8];
        acc[0][ni] = __builtin_amdgcn_mfma_f32_16x16x32_bf16(a0, b, acc[0][ni], 0, 0, 0);
        acc[1][ni] = __builtin_amdgcn_mfma_f32_16x16x32_bf16(a1, b, acc[1][ni], 0, 0, 0);
      }
    }
    __syncthreads();
  }

  const int b  = m0 / T_;
  const int bh = b * H_ + h;

  if (mat != 2) {
    // Q/K: direct [bh][t][d] write. Q folded scale = 1/8 * log2(e).
    const float qs = (mat == 0) ? 0.18033688f : 1.0f;
    ushort* outw = (mat == 0) ? q_ws : k_ws;
#pragma unroll
    for (int mi = 0; mi < 2; ++mi)
#pragma unroll
      for (int i = 0; i < 4; ++i) {
        const int t = m0 + w * 32 + mi * 16 + lk * 4 + i - b * T_;
        ushort* orow = outw + ((size_t)bh * T_ + t) * DH_;
#pragma unroll
        for (int ni = 0; ni < 4; ++ni)
          orow[ni * 16 + lrow] = f2bf(acc[mi][ni][i] * qs);
      }
  } else {
    // V: transpose 128x64 tile through LDS -> vt_ws[bh][d][t]
    ushort* Td = (ushort*)As;  // [64][TDS]
#pragma unroll
    for (int mi = 0; mi < 2; ++mi)
#pragma unroll
      for (int i = 0; i < 4; ++i) {
        const int tl = w * 32 + mi * 16 + lk * 4 + i;
#pragma unroll
        for (int ni = 0; ni < 4; ++ni)
          Td[(ni * 16 + lrow) * TDS + tl] = f2bf(acc[mi][ni][i]);
      }
    __syncthreads();
    const int t0 = m0 - b * T_;
#pragma unroll
    for (int it = 0; it < 4; ++it) {
      const int c = tid + it * 256;
      const int d = c >> 4, sub = c & 15;
      *(bf16x8*)(vt_ws + ((size_t)bh * DH_ + d) * T_ + t0 + sub * 8) =
          *(const bf16x8*)&Td[d * TDS + sub * 8];
    }
  }
}

// ---------------------------------------------------------------------------
// Causal flash attention, bf16 MFMA, swapped QK^T (S^T layout -> lane-local q).
// grid (x = bh = 24, y = 32, qt = 31 - y  => long blocks first, balanced/CU).
// Per k-tile: reg-prefetch next K/V, 2 shuffle-reduces, b64 P-store, exp2.
// ---------------------------------------------------------------------------
constexpr int LDK = 72;

__global__ __launch_bounds__(256) void attn_mfma_k(
    const ushort* __restrict__ q_ws, const ushort* __restrict__ k_ws,
    const ushort* __restrict__ vt_ws, ushort* __restrict__ o_ws)
{
  __shared__ __align__(16) ushort Ks[64 * LDK];      // K tile [s][d]
  __shared__ __align__(16) ushort Vt[64 * LDK];      // V^T tile [d][s]
  __shared__ __align__(16) ushort Pl[4][16 * LDK];   // per-wave P [q][s]

  const int qt = 31 - (int)blockIdx.y;
  const int bh = blockIdx.x;
  const int q0 = qt * 64;
  const ushort* Qb  = q_ws + (size_t)bh * T_ * DH_;
  const ushort* Kb  = k_ws + (size_t)bh * T_ * DH_;
  const ushort* VTb = vt_ws + (size_t)bh * DH_ * T_;

  const int tid  = threadIdx.x;
  const int w    = tid >> 6;
  const int l    = tid & 63;
  const int lrow = l & 15;
  const int lk   = l >> 4;
  const int rr   = tid >> 3;    // staging row 0..31
  const int sub  = tid & 7;     // staging 16B chunk

  // Q fragment (B-operand of swapped QK^T): lane holds Q[q=lrow][d=lk*8+r]
  const ushort* Qrow = Qb + (size_t)(q0 + w * 16 + lrow) * DH_;
  const bf16x8 qa0 = *(const bf16x8*)(Qrow + lk * 8);
  const bf16x8 qa1 = *(const bf16x8*)(Qrow + lk * 8 + 32);

  const int qglob = q0 + w * 16 + lrow;

  float m_r = -INFINITY, l_r = 0.f;
  f32x4 oc[4] = {};

  // prologue: load tile 0 into regs
  bf16x8 kp0, kp1, vp0, vp1;
  kp0 = *(const bf16x8*)(Kb + (size_t)rr * DH_ + sub * 8);
  kp1 = *(const bf16x8*)(Kb + (size_t)(rr + 32) * DH_ + sub * 8);
  vp0 = *(const bf16x8*)(VTb + (size_t)rr * T_ + sub * 8);
  vp1 = *(const bf16x8*)(VTb + (size_t)(rr + 32) * T_ + sub * 8);

  for (int kt = 0; kt <= qt; ++kt) {
    const int s0 = kt * 64;

    // commit staged regs to LDS
    *(bf16x8*)&Ks[rr * LDK + sub * 8]        = kp0;
    *(bf16x8*)&Ks[(rr + 32) * LDK + sub * 8] = kp1;
    *(bf16x8*)&Vt[rr * LDK + sub * 8]        = vp0;
    *(bf16x8*)&Vt[(rr + 32) * LDK + sub * 8] = vp1;
    __syncthreads();

    // prefetch next tile while computing this one
    if (kt < qt) {
      const int sn = s0 + 64;
      kp0 = *(const bf16x8*)(Kb + (size_t)(sn + rr) * DH_ + sub * 8);
      kp1 = *(const bf16x8*)(Kb + (size_t)(sn + rr + 32) * DH_ + sub * 8);
      vp0 = *(const bf16x8*)(VTb + (size_t)rr * T_ + sn + sub * 8);
      vp1 = *(const bf16x8*)(VTb + (size_t)(rr + 32) * T_ + sn + sub * 8);
    }

    // S^T = K Q^T : lane holds s = s0+ct*16+lk*4+i, q = lrow
    f32x4 st[4];
#pragma unroll
    for (int ct = 0; ct < 4; ++ct) {
      const bf16x8 kb0 = *(const bf16x8*)&Ks[(ct * 16 + lrow) * LDK + lk * 8];
      const bf16x8 kb1 = *(const bf16x8*)&Ks[(ct * 16 + lrow) * LDK + lk * 8 + 32];
      f32x4 z = {0.f, 0.f, 0.f, 0.f};
      z = __builtin_amdgcn_mfma_f32_16x16x32_bf16(kb0, qa0, z, 0, 0, 0);
      st[ct] = __builtin_amdgcn_mfma_f32_16x16x32_bf16(kb1, qa1, z, 0, 0, 0);
    }

    // per-lane online softmax over 16 in-lane s-values (+2 shuffles)
    const bool diag = (kt == qt);
    float mx = m_r;
#pragma unroll
    for (int ct = 0; ct < 4; ++ct)
#pragma unroll
      for (int i = 0; i < 4; ++i) {
        float sv = st[ct][i];
        if (diag && (s0 + ct * 16 + lk * 4 + i > qglob)) sv = -INFINITY;
        st[ct][i] = sv;
        mx = fmaxf(mx, sv);
      }
    mx = fmaxf(mx, __shfl_xor(mx, 16));
    mx = fmaxf(mx, __shfl_xor(mx, 32));
    const float corr = exp2f(m_r - mx);   // first tile: exp2(-inf)=0
    m_r = mx;
    float rs = 0.f;
#pragma unroll
    for (int ct = 0; ct < 4; ++ct)
#pragma unroll
      for (int i = 0; i < 4; ++i) {
        const float p = exp2f(st[ct][i] - mx);
        st[ct][i] = p;
        rs += p;
      }
    rs += __shfl_xor(rs, 16);
    rs += __shfl_xor(rs, 32);
    l_r = l_r * corr + rs;

    // P^T -> Pl[q][s] as packed bf16 (one b64 store per ct)
#pragma unroll
    for (int ct = 0; ct < 4; ++ct) {
      unsigned lo, hi;
      asm("v_cvt_pk_bf16_f32 %0, %1, %2" : "=v"(lo) : "v"(st[ct][0]), "v"(st[ct][1]));
      asm("v_cvt_pk_bf16_f32 %0, %1, %2" : "=v"(hi) : "v"(st[ct][2]), "v"(st[ct][3]));
      uint2 pk; pk.x = lo; pk.y = hi;
      *(uint2*)&Pl[w][lrow * LDK + ct * 16 + lk * 4] = pk;
    }

    // rescale O by per-q-row corr (broadcast from lanes 0..15)
#pragma unroll
    for (int i = 0; i < 4; ++i) {
      const float cr = __shfl(corr, lk * 4 + i);
#pragma unroll
      for (int ct = 0; ct < 4; ++ct) oc[ct][i] *= cr;
    }

    // O += P V
    const bf16x8 pa0 = *(const bf16x8*)&Pl[w][lrow * LDK + lk * 8];
    const bf16x8 pa1 = *(const bf16x8*)&Pl[w][lrow * LDK + lk * 8 + 32];
#pragma unroll
    for (int ct = 0; ct < 4; ++ct) {
      const bf16x8 vb0 = *(const bf16x8*)&Vt[(ct * 16 + lrow) * LDK + lk * 8];
      const bf16x8 vb1 = *(const bf16x8*)&Vt[(ct * 16 + lrow) * LDK + lk * 8 + 32];
      oc[ct] = __builtin_amdgcn_mfma_f32_16x16x32_bf16(pa0, vb0, oc[ct], 0, 0, 0);
      oc[ct] = __builtin_amdgcn_mfma_f32_16x16x32_bf16(pa1, vb1, oc[ct], 0, 0, 0);
    }
    __syncthreads();   // protect Ks/Vt for next tile
  }

  // epilogue: normalize (broadcast l), write concat-heads bf16
  const int bb = bh / H_, hh = bh - (bh / H_) * H_;
#pragma unroll
  for (int i = 0; i < 4; ++i) {
    const float lv  = __shfl(l_r, lk * 4 + i);
    const float inv = 1.0f / lv;
    const int t = q0 + w * 16 + lk * 4 + i;
    ushort* orow = o_ws + ((size_t)bb * T_ + t) * E_ + hh * DH_;
#pragma unroll
    for (int ct = 0; ct < 4; ++ct)
      orow[ct * 16 + lrow] = f2bf(oc[ct][i] * inv);
  }
}

// ---------------------------------------------------------------------------
// Out-proj MFMA GEMM: out = ob @ Wp + bp  (bf16 in, f32 out)
// ---------------------------------------------------------------------------
__global__ __launch_bounds__(256) void proj_mfma_k(
    const ushort* __restrict__ ob, const ushort* __restrict__ Wpt,
    const float* __restrict__ bp, float* __restrict__ out)
{
  __shared__ __align__(16) ushort As[128 * GLD];
  __shared__ __align__(16) ushort Bs[64 * GLD];

  const int n0 = blockIdx.x * 64;
  const int m0 = blockIdx.y * 128;

  const int tid  = threadIdx.x;
  const int w    = tid >> 6, l = tid & 63;
  const int lrow = l & 15, lk = l >> 4;

  f32x4 acc[2][4] = {};

  for (int k0 = 0; k0 < E_; k0 += 64) {
#pragma unroll
    for (int it = 0; it < 4; ++it) {
      const int c = tid + it * 256;
      const int r = c >> 3, sub = c & 7;
      *(bf16x8*)&As[r * GLD + sub * 8] =
          *(const bf16x8*)(ob + (size_t)(m0 + r) * E_ + k0 + sub * 8);
    }
#pragma unroll
    for (int it = 0; it < 2; ++it) {
      const int c = tid + it * 256;
      const int r = c >> 3, sub = c & 7;
      *(bf16x8*)&Bs[r * GLD + sub * 8] =
          *(const bf16x8*)(Wpt + (size_t)(n0 + r) * E_ + k0 + sub * 8);
    }
    __syncthreads();

#pragma unroll
    for (int kk = 0; kk < 2; ++kk) {
      const bf16x8 a0 = *(const bf16x8*)&As[(w * 32 + lrow) * GLD + kk * 32 + lk * 8];
      const bf16x8 a1 = *(const bf16x8*)&As[(w * 32 + 16 + lrow) * GLD + kk * 32 + lk * 8];
#pragma unroll
      for (int ni = 0; ni < 4; ++ni) {
        const bf16x8 b = *(const bf16x8*)&Bs[(ni * 16 + lrow) * GLD + kk * 32 + lk * 8];
        acc[0][ni] = __builtin_amdgcn_mfma_f32_16x16x32_bf16(a0, b, acc[0][ni], 0, 0, 0);
        acc[1][ni] = __builtin_amdgcn_mfma_f32_16x16x32_bf16(a1, b, acc[1][ni], 0, 0, 0);
      }
    }
    __syncthreads();
  }

  float bias[4];
#pragma unroll
  for (int ni = 0; ni < 4; ++ni) bias[ni] = bp[n0 + ni * 16 + lrow];

#pragma unroll
  for (int mi = 0; mi < 2; ++mi)
#pragma unroll
    for (int i = 0; i < 4; ++i) {
      const int m = m0 + w * 32 + mi * 16 + lk * 4 + i;
      float* orow = out + (size_t)m * E_ + n0;
#pragma unroll
      for (int ni = 0; ni < 4; ++ni)
        orow[ni * 16 + lrow] = acc[mi][ni][i] + bias[ni];
    }
}

}  // namespace

extern "C" void kernel_launch(void* const* d_in, const int* in_sizes, int n_in,
                              void* d_out, int out_size, void* d_ws, size_t ws_size,
                              hipStream_t stream) {
  const float* x  = (const float*)d_in[0];
  const float* Wq = (const float*)d_in[1];
  const float* Wk = (const float*)d_in[2];
  const float* Wv = (const float*)d_in[3];
  const float* Wp = (const float*)d_in[4];
  const float* bp = (const float*)d_in[5];
  float* out = (float*)d_out;

  const size_t nx  = (size_t)M_ * E_;
  const size_t nwt = (size_t)3 * H_ * DH_ * E_;
  const size_t nwp = (size_t)E_ * E_;
  const size_t per = (size_t)B_ * H_ * T_ * DH_;

  ushort* xb    = (ushort*)d_ws;
  ushort* Wt    = xb + nx;
  ushort* Wpt   = Wt + nwt;
  ushort* q_ws  = Wpt + nwp;
  ushort* k_ws  = q_ws + per;
  ushort* vt_ws = k_ws + per;   // [bh][d][t] transposed V
  ushort* o_b   = vt_ws + per;

  convert_x_k<<<dim3((int)(nx / (256 * 8))), 256, 0, stream>>>(x, xb);
  transpose_w_k<<<dim3(576), 256, 0, stream>>>(Wq, Wk, Wv, Wp, Wt, Wpt);
  qkv_mfma_k<<<dim3(36, 32), 256, 0, stream>>>(xb, Wt, q_ws, k_ws, vt_ws);
  attn_mfma_k<<<dim3(24, 32), 256, 0, stream>>>(q_ws, k_ws, vt_ws, o_b);
  proj_mfma_k<<<dim3(12, 32), 256, 0, stream>>>(o_b, Wpt, bp, out);
}